// Round 1
// baseline (296.512 us; speedup 1.0000x reference)
//
#include <hip/hip_runtime.h>

// Leaky LIF SNN forward, x/spk: [T=128, B*N=262144] fp32.
//   reset_t = H(mem_{t-1} - 1); mem_t = 0.5*mem_{t-1} + x_t - reset_t; spk_t = H(mem_t - 1)
//
// R5 theory: per-wave visits are 1KB @ 1MB stride; per-channel burst is capped
// by the ~256B interleave, so DRAM page locality can ONLY come from aggregate
// temporal coherence (all waves near the same row t => aggregate stream is
// address-sequential, like the 6.7 TB/s memset). Single phase (one read + one
// write per element, 268 MB total, no warmup amplification) with 65536 threads
// = 1 float4 column each, 256 blocks = 1/CU all-resident, marching t together.
// Drift is bounded by a PACING barrier every KWIN=8 rows: device-scope atomic
// arrive + bounded spin. Correctness never depends on the barrier (spin is
// iteration-capped -> no deadlock even if co-residency fails). D=8 prefetch
// keeps the next window's reads in flight across the barrier wait.

#define T_STEPS 128
#define D 8            // prefetch depth (rows in flight per thread: 8 KB/wave)
#define KWIN 8         // rows per pacing window (max inter-block drift)
#define NWIN (T_STEPS / KWIN)   // 16 windows, 15 barriers
#define NBLK 256
#define BLKT 256
#define SPIN_CAP 20000 // bounded spin: ~1 ms/window worst case, perf-only

__device__ __forceinline__ float4 lif_step(float4& mem, const float4 v) {
    // RHS evaluated with OLD mem (reset uses mem_{t-1})
    mem.x = 0.5f * mem.x + v.x - (mem.x > 1.0f ? 1.0f : 0.0f);
    mem.y = 0.5f * mem.y + v.y - (mem.y > 1.0f ? 1.0f : 0.0f);
    mem.z = 0.5f * mem.z + v.z - (mem.z > 1.0f ? 1.0f : 0.0f);
    mem.w = 0.5f * mem.w + v.w - (mem.w > 1.0f ? 1.0f : 0.0f);
    float4 s;
    s.x = mem.x > 1.0f ? 1.0f : 0.0f;
    s.y = mem.y > 1.0f ? 1.0f : 0.0f;
    s.z = mem.z > 1.0f ? 1.0f : 0.0f;
    s.w = mem.w > 1.0f ? 1.0f : 0.0f;
    return s;
}

__global__ __launch_bounds__(BLKT) void snn_leaky_fwd(const float4* __restrict__ x,
                                                      float4* __restrict__ out,
                                                      unsigned int* __restrict__ pace,
                                                      int n4) {
    const int col = blockIdx.x * BLKT + threadIdx.x;   // one float4 column/thread
    const float4* xp = x + col;
    float4* op = out + col;

    float4 buf[D];
    float4 mem = make_float4(0.f, 0.f, 0.f, 0.f);

#pragma unroll
    for (int u = 0; u < D; ++u) buf[u] = xp[(size_t)u * n4];

    for (int w = 0; w < NWIN; ++w) {
#pragma unroll
        for (int k = 0; k < KWIN; ++k) {
            const int t = w * KWIN + k;
            const float4 v = buf[k & (D - 1)];
            if (t + D < T_STEPS) buf[k & (D - 1)] = xp[(size_t)(t + D) * n4];
            const float4 s = lif_step(mem, v);
            op[(size_t)t * n4] = s;
        }
        if (w + 1 < NWIN) {
            // Pacing barrier: performance-only, never required for correctness.
            if (threadIdx.x == 0) {
                __hip_atomic_fetch_add(&pace[w], 1u, __ATOMIC_RELAXED,
                                       __HIP_MEMORY_SCOPE_AGENT);
                int spins = 0;
                for (;;) {
                    const unsigned int seen =
                        __hip_atomic_load(&pace[w], __ATOMIC_RELAXED,
                                          __HIP_MEMORY_SCOPE_AGENT);
                    if (seen >= (unsigned int)NBLK) break;
                    if (++spins >= SPIN_CAP) break;     // deadlock safety valve
                    __builtin_amdgcn_s_sleep(2);
                }
            }
            __syncthreads();
        }
    }
}

extern "C" void kernel_launch(void* const* d_in, const int* in_sizes, int n_in,
                              void* d_out, int out_size, void* d_ws, size_t ws_size,
                              hipStream_t stream) {
    const float4* x = (const float4*)d_in[0];
    float4* out = (float4*)d_out;

    const int total = in_sizes[0];            // T*B*N = 128*64*4096
    const int n4 = total / T_STEPS / 4;       // 65536 float4 columns

    unsigned int* pace = (unsigned int*)d_ws;
    hipMemsetAsync(pace, 0, NWIN * sizeof(unsigned int), stream);

    // 65536 threads = n4: every float4 column owned by exactly one thread,
    // 256 blocks -> 1 block/CU, all-resident, marching rows in lockstep.
    snn_leaky_fwd<<<NBLK, BLKT, 0, stream>>>(x, out, pace, n4);
}

// Round 2
// 225.206 us; speedup vs baseline: 1.3166x; 1.3166x over previous
//
#include <hip/hip_runtime.h>

// Leaky LIF SNN forward, x/spk: [T=128, B*N=262144] fp32.
//   reset_t = H(mem_{t-1} - 1); mem_t = 0.5*mem_{t-1} + x_t - reset_t; spk_t = H(mem_t - 1)
//
// R6: bench_dur ~= kernel_dur + ~145us fixed harness overhead (R0 kernel
// dispatches all <80us while bench read 224; R1: 150 -> 296). The working
// DRAM regime (R0, >=3.4 TB/s) is 8 waves/CU + >=1KB contiguous visit per
// block-row; R0 needed a 2-phase T-split (+67MB warmup re-reads) only
// because float4-per-thread capped threads at 65536. float2-per-thread
// gives 131072 threads = 512 blocks x 256 thr = 2 blocks/CU, 8 waves/CU,
// 2KB visits, SINGLE phase: exactly one read + one write per element
// (268 MB total, -20% traffic vs R0). D=16 rolling prefetch keeps 128B
// per thread in flight (~16.8 MB aggregate; Little's law needs ~6 MB).
// No barriers, no pacing (R5: global pacing collapsed MLP, -32%).

#define T_STEPS 128
#define D 16   // rolling ring depth (float2 rows in flight per thread)

__device__ __forceinline__ float2 lif_step(float2& mem, const float2 v) {
    // RHS uses OLD mem (reset term is H(mem_{t-1} - 1))
    mem.x = 0.5f * mem.x + v.x - (mem.x > 1.0f ? 1.0f : 0.0f);
    mem.y = 0.5f * mem.y + v.y - (mem.y > 1.0f ? 1.0f : 0.0f);
    float2 s;
    s.x = mem.x > 1.0f ? 1.0f : 0.0f;
    s.y = mem.y > 1.0f ? 1.0f : 0.0f;
    return s;
}

__global__ __launch_bounds__(256) void snn_leaky_fwd(const float2* __restrict__ x,
                                                     float2* __restrict__ out,
                                                     int n2) {
    const int col = blockIdx.x * 256 + threadIdx.x;   // one float2 column/thread
    const float2* xp = x + col;
    float2* op = out + col;

    float2 buf[D];
    float2 mem = make_float2(0.f, 0.f);

#pragma unroll
    for (int u = 0; u < D; ++u) buf[u] = xp[(size_t)u * n2];

#pragma unroll
    for (int t = 0; t < T_STEPS; ++t) {
        const float2 v = buf[t & (D - 1)];
        if (t + D < T_STEPS) buf[t & (D - 1)] = xp[(size_t)(t + D) * n2];
        const float2 s = lif_step(mem, v);
        op[(size_t)t * n2] = s;
    }
}

extern "C" void kernel_launch(void* const* d_in, const int* in_sizes, int n_in,
                              void* d_out, int out_size, void* d_ws, size_t ws_size,
                              hipStream_t stream) {
    const float2* x = (const float2*)d_in[0];
    float2* out = (float2*)d_out;

    const int total = in_sizes[0];            // T*B*N = 128*64*4096
    const int n2 = total / T_STEPS / 2;       // 131072 float2 columns

    // 512 blocks x 256 threads = 131072 threads = n2: every float2 column
    // owned by exactly one thread; 2 blocks/CU, 8 waves/CU, single phase.
    snn_leaky_fwd<<<n2 / 256, 256, 0, stream>>>(x, out, n2);
}